// Round 5
// baseline (2982.662 us; speedup 1.0000x reference)
//
#include <hip/hip_runtime.h>

// ---------- types ----------
typedef __attribute__((ext_vector_type(8))) short short8;
typedef __attribute__((ext_vector_type(8))) unsigned short ushort8;
typedef __attribute__((ext_vector_type(4))) float f32x4;

__device__ __forceinline__ float b2f(short s) {
    unsigned u = ((unsigned)(unsigned short)s) << 16;
    return __builtin_bit_cast(float, u);
}
__device__ __forceinline__ unsigned short f2b(float f) {
    unsigned u = __builtin_bit_cast(unsigned, f);
    u += 0x7fffu + ((u >> 16) & 1u);   // round-to-nearest-even
    return (unsigned short)(u >> 16);
}

// global -> LDS async copy, 16B per lane (wave-uniform LDS base + lane*16)
__device__ __forceinline__ void gload_lds16(const void* gptr, void* ldsptr) {
    typedef __attribute__((address_space(1))) const void gv_t;
    typedef __attribute__((address_space(3))) void lv_t;
    gv_t* g = reinterpret_cast<gv_t*>(reinterpret_cast<unsigned long long>(gptr));
    lv_t* l = reinterpret_cast<lv_t*>((unsigned int)reinterpret_cast<unsigned long long>(ldsptr));
    __builtin_amdgcn_global_load_lds(g, l, 16, 0, 0);
}

#define MEMFENCE() asm volatile("" ::: "memory")
#define BARRIER() do { MEMFENCE(); __builtin_amdgcn_s_barrier(); MEMFENCE(); } while (0)

// ---------- one-shot fp32->bf16 conversion for all inputs + bias concat ----------
// block ranges: [0,16384) x | [16384,16896) Wq | [16896,17408) Wk |
// [17408,17920) Wv | [17920,18432) Wo | 18432: biases (fp32 concat)
__global__ __launch_bounds__(256) void cvt_all(const float* __restrict__ x,
                                               const float* __restrict__ Wq,
                                               const float* __restrict__ Wk,
                                               const float* __restrict__ Wv,
                                               const float* __restrict__ Wo,
                                               const float* __restrict__ bq,
                                               const float* __restrict__ bk,
                                               const float* __restrict__ bv,
                                               unsigned short* __restrict__ xb,
                                               unsigned short* __restrict__ wqkv,
                                               unsigned short* __restrict__ wo,
                                               float* __restrict__ bqkv) {
    const int bid = blockIdx.x;
    const float* src;
    unsigned short* dst;
    int base8;
    if (bid < 16384)      { src = x;  dst = xb;              base8 = bid; }
    else if (bid < 16896) { src = Wq; dst = wqkv;            base8 = bid - 16384; }
    else if (bid < 17408) { src = Wk; dst = wqkv + 1048576;  base8 = bid - 16896; }
    else if (bid < 17920) { src = Wv; dst = wqkv + 2097152;  base8 = bid - 17408; }
    else if (bid < 18432) { src = Wo; dst = wo;              base8 = bid - 17920; }
    else {
        const int i = threadIdx.x;
#pragma unroll
        for (int r = 0; r < 12; ++r) {   // 3072 floats
            int j = r * 256 + i;
            float v = (j < 1024) ? bq[j] : (j < 2048 ? bk[j - 1024] : bv[j - 2048]);
            bqkv[j] = v;
        }
        return;
    }
    const size_t i8 = (size_t)base8 * 256 + threadIdx.x;
    const float4* p = (const float4*)src + i8 * 2;
    float4 a = p[0], b = p[1];
    ushort8 o;
    o[0] = f2b(a.x); o[1] = f2b(a.y); o[2] = f2b(a.z); o[3] = f2b(a.w);
    o[4] = f2b(b.x); o[5] = f2b(b.y); o[6] = f2b(b.z); o[7] = f2b(b.w);
    *(ushort8*)(dst + i8 * 8) = o;
}

// ---------- bf16 GEMM, C[m,n] = sum_k A[m,k]*B[n,k] + bias[n] ----------
// 256x256 tile, BK=32, 512 threads (8 waves, 2x4), per-wave out 128x64.
// LDS 64 KiB: [2 dbuf][A 256x32 | B 256x32] bf16 -> 2 BLOCKS/CU co-resident.
// The overlap mechanism is cross-block (m114/m97): while one block drains its
// LDS reads at a barrier, the other block's waves feed the matrix pipe. Simple
// 2-barrier loop with counted vmcnt(4) (next tile's 4 gloads stay in flight).
// Swizzle (64B rows, 4 granules): phys granule = G ^ ((row>>1)&3); stage
// source pre-swizzled (lane l supplies logical granule (l&3)^((l>>3)&3)) since
// global_load_lds writes linearly. 8 lanes/bank-group balanced -> conflict-free.
// BK=32 => each acc[m][n] touched once per tile (no MFMA dep stalls).
template <bool OUT_BF16>
__global__ __launch_bounds__(512, 4) void gemm_bt(const short* __restrict__ A,   // [M,K] bf16
                                                  const short* __restrict__ B,   // [N,K] bf16
                                                  const float* __restrict__ bias,// [N]
                                                  unsigned short* __restrict__ Cb,
                                                  float* __restrict__ Cf,
                                                  int M, int N, int K) {
    extern __shared__ short lds[];          // [2][8192 A | 8192 B] shorts = 64 KiB
    const int lane = threadIdx.x & 63;
    const int wave = threadIdx.x >> 6;
    const int wr = wave >> 2;      // 0..1: wave row (128 rows)
    const int wc = wave & 3;       // 0..3: wave col (64 cols)

    // XCD-aware swizzle (grid % 8 == 0 for both calls)
    const int nwg = gridDim.x;
    const int bid = blockIdx.x;
    const int swz = (bid & 7) * (nwg >> 3) + (bid >> 3);
    const int ncol = N >> 8;
    const int trow = swz / ncol, tcol = swz % ncol;

    const short* Ablk = A + (size_t)trow * 256 * K;
    const short* Bblk = B + (size_t)tcol * 256 * K;

    // staging: lane l -> row l>>2 of 16-row stripe, phys granule l&3 (linear dest);
    // global source supplies logical granule (l&3) ^ ((l>>3)&3)
    const int s_r = lane >> 2;
    const int s_c = ((lane & 3) ^ ((lane >> 3) & 3)) * 8;
    // frag read: row = base + m*16 + rl; logical granule G = lane>>4 at
    // phys = G ^ ((rl>>1)&3)  (base multiples of 16 drop out)
    const int rl = lane & 15;
    const int gph = ((lane >> 4) ^ ((rl >> 1) & 3)) * 8;

    short8 af[8], bfr[4];
    f32x4 acc[8][4] = {};

    const int NT = K >> 5;

    auto stage = [&](int t, int b) {
#pragma unroll
        for (int c = 0; c < 2; ++c) {
            const int R0 = (c * 8 + wave) * 16;            // wave-uniform stripe base
            gload_lds16(Ablk + (size_t)(R0 + s_r) * K + t * 32 + s_c,
                        lds + b * 8192 + R0 * 32);
            gload_lds16(Bblk + (size_t)(R0 + s_r) * K + t * 32 + s_c,
                        lds + 16384 + b * 8192 + R0 * 32);
        }
    };

    // prologue
    stage(0, 0);

    for (int t = 0; t < NT; ++t) {
        const int b = t & 1;
        if (t + 1 < NT) {
            stage(t + 1, b ^ 1);
            asm volatile("s_waitcnt vmcnt(4)" ::: "memory");   // tile t landed; t+1 in flight
        } else {
            asm volatile("s_waitcnt vmcnt(0)" ::: "memory");
        }
        BARRIER();   // all waves' tile-t stages landed; prev reads of b^1 done

        // reads: B first, then A (first MFMA exposes only ~5 of 12 reads)
        {
            const short* bbase = lds + 16384 + b * 8192 + (wc * 64 + rl) * 32 + gph;
#pragma unroll
            for (int n = 0; n < 4; ++n) bfr[n] = *(const short8*)(bbase + n * 16 * 32);
            const short* abase = lds + b * 8192 + (wr * 128 + rl) * 32 + gph;
#pragma unroll
            for (int m = 0; m < 8; ++m) af[m] = *(const short8*)(abase + m * 16 * 32);
        }
        __builtin_amdgcn_s_setprio(1);
#pragma unroll
        for (int m = 0; m < 8; ++m)
#pragma unroll
            for (int n = 0; n < 4; ++n)
                acc[m][n] = __builtin_amdgcn_mfma_f32_16x16x32_bf16(af[m], bfr[n], acc[m][n], 0, 0, 0);
        __builtin_amdgcn_s_setprio(0);
        BARRIER();   // reads of buf b done before it is re-staged next iter
    }

    // epilogue: C/D layout col = lane&15, row = (lane>>4)*4 + r
    const int crow0 = trow * 256 + wr * 128 + (lane >> 4) * 4;
    const int ccol0 = tcol * 256 + wc * 64 + rl;
#pragma unroll
    for (int n = 0; n < 4; ++n) {
        const int col = ccol0 + n * 16;
        const float bv = bias[col];
#pragma unroll
        for (int m = 0; m < 8; ++m) {
            const int row0 = crow0 + m * 16;
#pragma unroll
            for (int r = 0; r < 4; ++r) {
                float val = acc[m][n][r] + bv;
                if (OUT_BF16) Cb[(size_t)(row0 + r) * N + col] = f2b(val);
                else          Cf[(size_t)(row0 + r) * N + col] = val;
            }
        }
    }
}

// ---------- per-token cross-head attention ----------
// qkv: [N, 3072] bf16 (q | k | v), out: [N, 1024] bf16
// one thread per (token, head): 16x16 scores, softmax over key-heads, 16x64 PV
__global__ __launch_bounds__(256) void attn_k(const short* __restrict__ qkv,
                                              short* __restrict__ out) {
    int gid = blockIdx.x * 256 + threadIdx.x;
    int t = gid >> 4, h = gid & 15;
    const short* q  = qkv + (size_t)t * 3072 + h * 64;
    const short* kb = qkv + (size_t)t * 3072 + 1024;
    const short* vb = qkv + (size_t)t * 3072 + 2048;

    float qf[64];
#pragma unroll
    for (int j = 0; j < 8; ++j) {
        short8 qv = *(const short8*)(q + j * 8);
#pragma unroll
        for (int i = 0; i < 8; ++i) qf[j * 8 + i] = b2f(qv[i]);
    }

    float s[16];
    float mx = -1e30f;
#pragma unroll
    for (int g = 0; g < 16; ++g) {
        float a = 0.f;
#pragma unroll
        for (int j = 0; j < 8; ++j) {
            short8 kv = *(const short8*)(kb + g * 64 + j * 8);
#pragma unroll
            for (int i = 0; i < 8; ++i) a += qf[j * 8 + i] * b2f(kv[i]);
        }
        s[g] = a * 0.125f;   // scale = 1/sqrt(64)
        mx = fmaxf(mx, s[g]);
    }
    float den = 0.f;
#pragma unroll
    for (int g = 0; g < 16; ++g) { s[g] = __expf(s[g] - mx); den += s[g]; }
    float inv = 1.f / den;

#pragma unroll
    for (int j = 0; j < 8; ++j) {
        float o[8] = {0.f, 0.f, 0.f, 0.f, 0.f, 0.f, 0.f, 0.f};
#pragma unroll
        for (int g = 0; g < 16; ++g) {
            short8 vv = *(const short8*)(vb + g * 64 + j * 8);
            float w = s[g];
#pragma unroll
            for (int i = 0; i < 8; ++i) o[i] += w * b2f(vv[i]);
        }
        short8 ov;
#pragma unroll
        for (int i = 0; i < 8; ++i) ov[i] = (short)f2b(o[i] * inv);
        *(short8*)(out + (size_t)t * 1024 + h * 64 + j * 8) = ov;
    }
}

// ---------- launch ----------
extern "C" void kernel_launch(void* const* d_in, const int* in_sizes, int n_in,
                              void* d_out, int out_size, void* d_ws, size_t ws_size,
                              hipStream_t stream) {
    const float* x  = (const float*)d_in[0];
    const float* Wq = (const float*)d_in[1];
    const float* bq = (const float*)d_in[2];
    const float* Wk = (const float*)d_in[3];
    const float* bk = (const float*)d_in[4];
    const float* Wv = (const float*)d_in[5];
    const float* bv = (const float*)d_in[6];
    const float* Wo = (const float*)d_in[7];
    const float* bo = (const float*)d_in[8];
    float* out = (float*)d_out;

    const int N = 32768, E = 1024;
    const int LDS_BYTES = 65536;

    (void)hipFuncSetAttribute((const void*)gemm_bt<true>,  hipFuncAttributeMaxDynamicSharedMemorySize, LDS_BYTES);
    (void)hipFuncSetAttribute((const void*)gemm_bt<false>, hipFuncAttributeMaxDynamicSharedMemorySize, LDS_BYTES);

    char* ws = (char*)d_ws;
    size_t off = 0;
    short* xb = (short*)(ws + off);         off += (size_t)N * E * 2;          // 64 MiB
    short* wqkv = (short*)(ws + off);       off += (size_t)3 * E * E * 2;      // 6 MiB
    short* wo = (short*)(ws + off);         off += (size_t)E * E * 2;          // 2 MiB
    float* bqkv = (float*)(ws + off);       off += (size_t)3 * E * 4;          // 12 KiB
    off = (off + 255) & ~(size_t)255;
    short* y1 = (short*)(ws + off);         off += (size_t)N * 3 * E * 2;      // 192 MiB
    short* ao = xb;  // reuse xb region: dead after GEMM1, attn writes here

    // 1) one fused conversion kernel (x, Wq, Wk, Wv, Wo, bias-concat)
    cvt_all<<<dim3(18433), dim3(256), 0, stream>>>(
        x, Wq, Wk, Wv, Wo, bq, bk, bv,
        (unsigned short*)xb, (unsigned short*)wqkv, (unsigned short*)wo, bqkv);

    // 2) fused QKV projection: y1[N, 3072] = xb @ wqkv^T + bqkv  (bf16 out)
    //    grid = (32768/256)*(3072/256) = 1536 blocks (%8==0)
    gemm_bt<true><<<dim3((N / 256) * (3 * E / 256)), dim3(512), LDS_BYTES, stream>>>(
        xb, wqkv, bqkv, (unsigned short*)y1, nullptr, N, 3 * E, E);

    // 3) per-token attention: ao[N, 1024] bf16
    attn_k<<<dim3(N * 16 / 256), dim3(256), 0, stream>>>(y1, ao);

    // 4) output projection: out[N, 1024] = ao @ wo^T + bo  (fp32 out)
    //    grid = 128*4 = 512 blocks (%8==0), all co-resident at 2 blocks/CU
    gemm_bt<false><<<dim3((N / 256) * (E / 256)), dim3(512), LDS_BYTES, stream>>>(
        ao, wo, bo, nullptr, out, N, E, E);
}

// Round 6
// 478.714 us; speedup vs baseline: 6.2306x; 6.2306x over previous
//
#include <hip/hip_runtime.h>

// ---------- types ----------
typedef __attribute__((ext_vector_type(8))) short short8;
typedef __attribute__((ext_vector_type(8))) unsigned short ushort8;
typedef __attribute__((ext_vector_type(4))) float f32x4;

__device__ __forceinline__ float b2f(short s) {
    unsigned u = ((unsigned)(unsigned short)s) << 16;
    return __builtin_bit_cast(float, u);
}
__device__ __forceinline__ unsigned short f2b(float f) {
    unsigned u = __builtin_bit_cast(unsigned, f);
    u += 0x7fffu + ((u >> 16) & 1u);   // round-to-nearest-even
    return (unsigned short)(u >> 16);
}

// global -> LDS async copy, 16B per lane (wave-uniform LDS base + lane*16)
__device__ __forceinline__ void gload_lds16(const void* gptr, void* ldsptr) {
    typedef __attribute__((address_space(1))) const void gv_t;
    typedef __attribute__((address_space(3))) void lv_t;
    gv_t* g = reinterpret_cast<gv_t*>(reinterpret_cast<unsigned long long>(gptr));
    lv_t* l = reinterpret_cast<lv_t*>((unsigned int)reinterpret_cast<unsigned long long>(ldsptr));
    __builtin_amdgcn_global_load_lds(g, l, 16, 0, 0);
}

#define MEMFENCE() asm volatile("" ::: "memory")
#define BARRIER() do { MEMFENCE(); __builtin_amdgcn_s_barrier(); MEMFENCE(); } while (0)

// ---------- one-shot fp32->bf16 conversion for all inputs + bias concat ----------
__global__ __launch_bounds__(256) void cvt_all(const float* __restrict__ x,
                                               const float* __restrict__ Wq,
                                               const float* __restrict__ Wk,
                                               const float* __restrict__ Wv,
                                               const float* __restrict__ Wo,
                                               const float* __restrict__ bq,
                                               const float* __restrict__ bk,
                                               const float* __restrict__ bv,
                                               unsigned short* __restrict__ xb,
                                               unsigned short* __restrict__ wqkv,
                                               unsigned short* __restrict__ wo,
                                               float* __restrict__ bqkv) {
    const int bid = blockIdx.x;
    const float* src;
    unsigned short* dst;
    int base8;
    if (bid < 16384)      { src = x;  dst = xb;              base8 = bid; }
    else if (bid < 16896) { src = Wq; dst = wqkv;            base8 = bid - 16384; }
    else if (bid < 17408) { src = Wk; dst = wqkv + 1048576;  base8 = bid - 16896; }
    else if (bid < 17920) { src = Wv; dst = wqkv + 2097152;  base8 = bid - 17408; }
    else if (bid < 18432) { src = Wo; dst = wo;              base8 = bid - 17920; }
    else {
        const int i = threadIdx.x;
#pragma unroll
        for (int r = 0; r < 12; ++r) {   // 3072 floats
            int j = r * 256 + i;
            float v = (j < 1024) ? bq[j] : (j < 2048 ? bk[j - 1024] : bv[j - 2048]);
            bqkv[j] = v;
        }
        return;
    }
    const size_t i8 = (size_t)base8 * 256 + threadIdx.x;
    const float4* p = (const float4*)src + i8 * 2;
    float4 a = p[0], b = p[1];
    ushort8 o;
    o[0] = f2b(a.x); o[1] = f2b(a.y); o[2] = f2b(a.z); o[3] = f2b(a.w);
    o[4] = f2b(b.x); o[5] = f2b(b.y); o[6] = f2b(b.z); o[7] = f2b(b.w);
    *(ushort8*)(dst + i8 * 8) = o;
}

// ---------- GEMM A (R4-proven): 256x256, BK=64, 4-phase quadrant, 128 KiB ----------
template <bool OUT_BF16>
__global__ __launch_bounds__(512, 2) void gemm_bt(const short* __restrict__ A,
                                                  const short* __restrict__ B,
                                                  const float* __restrict__ bias,
                                                  unsigned short* __restrict__ Cb,
                                                  float* __restrict__ Cf,
                                                  int M, int N, int K) {
    extern __shared__ short lds[];
    short* Ab = lds;                       // [2][2][128][64]
    short* Bb = lds + 2 * 2 * 128 * 64;    // [2][2][128][64]

    const int lane = threadIdx.x & 63;
    const int wave = threadIdx.x >> 6;
    const int wr = wave >> 2;
    const int wc = wave & 3;

    const int nwg = gridDim.x;
    const int bid = blockIdx.x;
    const int swz = (bid & 7) * (nwg >> 3) + (bid >> 3);
    const int ncol = N >> 8;
    const int trow = swz / ncol, tcol = swz % ncol;

    const short* Ablk = A + (size_t)trow * 256 * K;
    const short* Bblk = B + (size_t)tcol * 256 * K;

    const int scol_sw = ((lane & 7) ^ (lane >> 3)) * 8;
    const int rl = lane & 15;
    const int g0 = (((lane >> 4)) ^ (lane & 7)) * 8;
    const int g1 = ((4 + (lane >> 4)) ^ (lane & 7)) * 8;

    short8 af[4][2];
    short8 bf[4][2];
    f32x4 acc[8][4] = {};

    const int NT = K >> 6;
    const int smax = 4 * (NT - 2);

    auto stage_half = [&](int ts, int h) {
        const int dd = ts & 1;
        const int hh = h & 1;
        const short* gb = ((h < 2) ? Ablk : Bblk) + (size_t)(hh * 128) * K + (ts << 6) + scol_sw;
        short* lb = ((h < 2) ? Ab : Bb) + (((dd << 1) | hh) << 13);
#pragma unroll
        for (int c = 0; c < 2; ++c) {
            const int row = c * 64 + wave * 8 + (lane >> 3);
            gload_lds16(gb + (size_t)row * K, lb + ((c * 64 + wave * 8) << 6));
        }
    };
    auto stage_if = [&](int s) { if (s >= 0 && s < smax) stage_half((s >> 2) + 2, s & 3); };

    auto readA = [&](int d, int mh) {
        const short* base = Ab + (((d << 1) | wr) << 13) + ((mh * 64 + rl) << 6);
#pragma unroll
        for (int m = 0; m < 4; ++m) {
            af[m][0] = *(const short8*)(base + ((m * 16) << 6) + g0);
            af[m][1] = *(const short8*)(base + ((m * 16) << 6) + g1);
        }
    };
    auto readB = [&](int d, int nh) {
        const short* base = Bb + (((d << 1) | (wc >> 1)) << 13) + (((wc & 1) * 64 + rl) << 6);
#pragma unroll
        for (int j = 0; j < 2; ++j) {
            bf[nh * 2 + j][0] = *(const short8*)(base + (((nh * 2 + j) * 16) << 6) + g0);
            bf[nh * 2 + j][1] = *(const short8*)(base + (((nh * 2 + j) * 16) << 6) + g1);
        }
    };
    auto mm = [&](int mh, int nh) {
        __builtin_amdgcn_s_setprio(1);
#pragma unroll
        for (int ks = 0; ks < 2; ++ks)
#pragma unroll
            for (int m = 0; m < 4; ++m)
#pragma unroll
                for (int j = 0; j < 2; ++j)
                    acc[mh * 4 + m][nh * 2 + j] = __builtin_amdgcn_mfma_f32_16x16x32_bf16(
                        af[m][ks], bf[nh * 2 + j][ks], acc[mh * 4 + m][nh * 2 + j], 0, 0, 0);
        __builtin_amdgcn_s_setprio(0);
    };

    auto tile_body = [&](int T, int d) {
        const int s0 = 4 * T;
        readA(d, 0); readB(d, 0);
        stage_if(s0 - 3);
        asm volatile("s_waitcnt lgkmcnt(8)" ::: "memory");
        BARRIER();
        asm volatile("s_waitcnt lgkmcnt(0)" ::: "memory");
        mm(0, 0);
        BARRIER();
        readB(d, 1);
        stage_if(s0 - 2);
        BARRIER();
        asm volatile("s_waitcnt lgkmcnt(0)" ::: "memory");
        mm(0, 1);
        BARRIER();
        readA(d, 1);
        stage_if(s0 - 1);
        BARRIER();
        asm volatile("s_waitcnt lgkmcnt(0)" ::: "memory");
        mm(1, 0);
        BARRIER();
        stage_if(s0);
        BARRIER();
        mm(1, 1);
        if (T < NT - 2)       asm volatile("s_waitcnt vmcnt(2)" ::: "memory");
        else if (T == NT - 2) asm volatile("s_waitcnt vmcnt(0)" ::: "memory");
        BARRIER();
    };

#pragma unroll
    for (int t = 0; t < 2; ++t)
#pragma unroll
        for (int h = 0; h < 4; ++h) stage_half(t, h);
    asm volatile("s_waitcnt vmcnt(8)" ::: "memory");
    BARRIER();

    for (int T2 = 0; T2 < NT; T2 += 2) {
        tile_body(T2, 0);
        tile_body(T2 + 1, 1);
    }

    const int crow0 = trow * 256 + wr * 128 + (lane >> 4) * 4;
    const int ccol0 = tcol * 256 + wc * 64 + rl;
#pragma unroll
    for (int n = 0; n < 4; ++n) {
        const int col = ccol0 + n * 16;
        const float bv = bias[col];
#pragma unroll
        for (int m = 0; m < 8; ++m) {
            const int row0 = crow0 + m * 16;
#pragma unroll
            for (int r = 0; r < 4; ++r) {
                float val = acc[m][n][r] + bv;
                if (OUT_BF16) Cb[(size_t)(row0 + r) * N + col] = f2b(val);
                else          Cf[(size_t)(row0 + r) * N + col] = val;
            }
        }
    }
}

// ---------- GEMM B (experimental, G2 only): 256x256, BK=32, frag-prefetch ----------
// Per tile (buf b=t&1), 4 quadrant-phases Q0=(A0,B0) Q1=(A1,B0) Q2=(A0,B1)
// Q3=(A1,B1); each quadrant's ds_reads are issued >=1 phase before its MFMA
// (counted lgkm), so every drain hides under the previous quadrant's MFMA.
// Tile-boundary Q0' reads issue after the publish barrier and drain under Q3.
// 2 barriers/tile: mid (end-P1; protects same-tile A.h0 restage at P3) and
// end (publish t+1; vmcnt(1) leaves only s=4t in flight).
// Staging stream: s=4t+q-3 at phase q -> tile (s>>2)+2, half s&3
// (0:A.h0 1:A.h1 2:B.h0 3:B.h1), 1 gload each. Swizzle identical to R5's
// correctness-proven math (granule ^= (row>>1)&3, 0 conflicts measured).
#define MMQ(AF, BF, MB, NB)                                                            \
    do {                                                                               \
        __builtin_amdgcn_s_setprio(1);                                                 \
        _Pragma("unroll")                                                              \
        for (int m_ = 0; m_ < 4; ++m_)                                                 \
            _Pragma("unroll")                                                          \
            for (int n_ = 0; n_ < 2; ++n_)                                             \
                acc[(MB) + m_][(NB) + n_] = __builtin_amdgcn_mfma_f32_16x16x32_bf16(   \
                    AF[m_], BF[n_], acc[(MB) + m_][(NB) + n_], 0, 0, 0);               \
        __builtin_amdgcn_s_setprio(0);                                                 \
    } while (0)

__global__ __launch_bounds__(512, 2) void gemm_pf(const short* __restrict__ A,   // [M,K]
                                                  const short* __restrict__ B,   // [N,K]
                                                  const float* __restrict__ bias,
                                                  float* __restrict__ Cf,
                                                  int M, int N, int K) {
    extern __shared__ short lds[];   // A [2][256][32] | B [2][256][32] = 64 KiB
    const int lane = threadIdx.x & 63;
    const int wave = threadIdx.x >> 6;
    const int wr = wave >> 2;
    const int wc = wave & 3;

    const int nwg = gridDim.x;
    const int bid = blockIdx.x;
    const int swz = (bid & 7) * (nwg >> 3) + (bid >> 3);
    const int ncol = N >> 8;
    const int trow = swz / ncol, tcol = swz % ncol;

    const short* Ablk = A + (size_t)trow * 256 * K;
    const short* Bblk = B + (size_t)tcol * 256 * K;

    // staging (R5-proven): lane l -> row l>>2 of 16-row stripe, phys granule l&3
    const int s_r = lane >> 2;
    const int s_c = ((lane & 3) ^ ((lane >> 3) & 3)) * 8;
    // frag read (R5-proven): logical granule lane>>4 at phys ^ ((row>>1)&3)
    const int rl = lane & 15;
    const int gph = ((lane >> 4) ^ ((rl >> 1) & 3)) * 8;

    short8 af0[4], af1[4], bf0[2], bf1[2];
    f32x4 acc[8][4] = {};

    const int NT = K >> 5;
    const int smax = 4 * (NT - 2);

    auto stage_half = [&](int ts, int h) {
        const int dd = ts & 1;
        const int hh = h & 1;
        const int R0 = hh * 128 + wave * 16;
        const short* gb = (h < 2) ? Ablk : Bblk;
        short* lb = lds + ((h < 2) ? 0 : 16384) + dd * 8192;
        gload_lds16(gb + (size_t)(R0 + s_r) * K + (ts << 5) + s_c, lb + R0 * 32);
    };
    auto stage_if = [&](int s) { if (s >= 0 && s < smax) stage_half((s >> 2) + 2, s & 3); };

    auto readA0 = [&](int d) {
        const short* base = lds + d * 8192 + (wr * 128 + rl) * 32 + gph;
#pragma unroll
        for (int m = 0; m < 4; ++m) af0[m] = *(const short8*)(base + m * 16 * 32);
    };
    auto readA1 = [&](int d) {
        const short* base = lds + d * 8192 + (wr * 128 + 64 + rl) * 32 + gph;
#pragma unroll
        for (int m = 0; m < 4; ++m) af1[m] = *(const short8*)(base + m * 16 * 32);
    };
    auto readB0 = [&](int d) {
        const short* base = lds + 16384 + d * 8192 + (wc * 64 + rl) * 32 + gph;
#pragma unroll
        for (int j = 0; j < 2; ++j) bf0[j] = *(const short8*)(base + j * 16 * 32);
    };
    auto readB1 = [&](int d) {
        const short* base = lds + 16384 + d * 8192 + (wc * 64 + 32 + rl) * 32 + gph;
#pragma unroll
        for (int j = 0; j < 2; ++j) bf1[j] = *(const short8*)(base + j * 16 * 32);
    };

    // prologue: stage tiles 0,1 (8 gloads); tile0 landed; pre-issue Q0 reads
#pragma unroll
    for (int t = 0; t < 2; ++t)
#pragma unroll
        for (int h = 0; h < 4; ++h) stage_half(t, h);
    asm volatile("s_waitcnt vmcnt(4)" ::: "memory");
    BARRIER();
    readA0(0); readB0(0);

    for (int t = 0; t < NT; ++t) {
        const int d = t & 1;
        const int s0 = 4 * t;
        // P0: Q0 = A0 x B0 ; prefetch A1
        stage_if(s0 - 3);
        readA1(d);
        asm volatile("s_waitcnt lgkmcnt(4)" ::: "memory");   // A0,B0 serviced
        MMQ(af0, bf0, 0, 0);
        // P1: Q1 = A1 x B0 ; prefetch B1
        stage_if(s0 - 2);
        readB1(d);
        asm volatile("s_waitcnt lgkmcnt(2)" ::: "memory");   // A1 serviced
        MMQ(af1, bf0, 4, 0);
        BARRIER();   // mid: all waves' A-reads of tile t serviced (P3 A.h0 restage safe)
        // P2: Q2 = A0 x B1
        stage_if(s0 - 1);
        asm volatile("s_waitcnt lgkmcnt(0)" ::: "memory");   // B1 serviced
        MMQ(af0, bf1, 0, 2);
        // P3: publish t+1, then Q0' reads drain under Q3
        stage_if(s0);
        if (t < NT - 2) asm volatile("s_waitcnt vmcnt(1)" ::: "memory");
        else            asm volatile("s_waitcnt vmcnt(0)" ::: "memory");
        BARRIER();   // end: tile t+1 visible
        if (t + 1 < NT) { readA0(d ^ 1); readB0(d ^ 1); }
        asm volatile("s_waitcnt lgkmcnt(6)" ::: "memory");   // af1/bf1 already serviced
        MMQ(af1, bf1, 4, 2);
    }

    const int crow0 = trow * 256 + wr * 128 + (lane >> 4) * 4;
    const int ccol0 = tcol * 256 + wc * 64 + rl;
#pragma unroll
    for (int n = 0; n < 4; ++n) {
        const int col = ccol0 + n * 16;
        const float bv = bias[col];
#pragma unroll
        for (int m = 0; m < 8; ++m) {
            const int row0 = crow0 + m * 16;
#pragma unroll
            for (int r = 0; r < 4; ++r)
                Cf[(size_t)(row0 + r) * N + col] = acc[m][n][r] + bv;
        }
    }
}

// ---------- per-token cross-head attention ----------
__global__ __launch_bounds__(256) void attn_k(const short* __restrict__ qkv,
                                              short* __restrict__ out) {
    int gid = blockIdx.x * 256 + threadIdx.x;
    int t = gid >> 4, h = gid & 15;
    const short* q  = qkv + (size_t)t * 3072 + h * 64;
    const short* kb = qkv + (size_t)t * 3072 + 1024;
    const short* vb = qkv + (size_t)t * 3072 + 2048;

    float qf[64];
#pragma unroll
    for (int j = 0; j < 8; ++j) {
        short8 qv = *(const short8*)(q + j * 8);
#pragma unroll
        for (int i = 0; i < 8; ++i) qf[j * 8 + i] = b2f(qv[i]);
    }

    float s[16];
    float mx = -1e30f;
#pragma unroll
    for (int g = 0; g < 16; ++g) {
        float a = 0.f;
#pragma unroll
        for (int j = 0; j < 8; ++j) {
            short8 kv = *(const short8*)(kb + g * 64 + j * 8);
#pragma unroll
            for (int i = 0; i < 8; ++i) a += qf[j * 8 + i] * b2f(kv[i]);
        }
        s[g] = a * 0.125f;
        mx = fmaxf(mx, s[g]);
    }
    float den = 0.f;
#pragma unroll
    for (int g = 0; g < 16; ++g) { s[g] = __expf(s[g] - mx); den += s[g]; }
    float inv = 1.f / den;

#pragma unroll
    for (int j = 0; j < 8; ++j) {
        float o[8] = {0.f, 0.f, 0.f, 0.f, 0.f, 0.f, 0.f, 0.f};
#pragma unroll
        for (int g = 0; g < 16; ++g) {
            short8 vv = *(const short8*)(vb + g * 64 + j * 8);
            float w = s[g];
#pragma unroll
            for (int i = 0; i < 8; ++i) o[i] += w * b2f(vv[i]);
        }
        short8 ov;
#pragma unroll
        for (int i = 0; i < 8; ++i) ov[i] = (short)f2b(o[i] * inv);
        *(short8*)(out + (size_t)t * 1024 + h * 64 + j * 8) = ov;
    }
}

// ---------- launch ----------
extern "C" void kernel_launch(void* const* d_in, const int* in_sizes, int n_in,
                              void* d_out, int out_size, void* d_ws, size_t ws_size,
                              hipStream_t stream) {
    const float* x  = (const float*)d_in[0];
    const float* Wq = (const float*)d_in[1];
    const float* bq = (const float*)d_in[2];
    const float* Wk = (const float*)d_in[3];
    const float* bk = (const float*)d_in[4];
    const float* Wv = (const float*)d_in[5];
    const float* bv = (const float*)d_in[6];
    const float* Wo = (const float*)d_in[7];
    const float* bo = (const float*)d_in[8];
    float* out = (float*)d_out;

    const int N = 32768, E = 1024;

    (void)hipFuncSetAttribute((const void*)gemm_bt<true>, hipFuncAttributeMaxDynamicSharedMemorySize, 131072);
    (void)hipFuncSetAttribute((const void*)gemm_pf,       hipFuncAttributeMaxDynamicSharedMemorySize, 65536);

    char* ws = (char*)d_ws;
    size_t off = 0;
    short* xb = (short*)(ws + off);         off += (size_t)N * E * 2;
    short* wqkv = (short*)(ws + off);       off += (size_t)3 * E * E * 2;
    short* wo = (short*)(ws + off);         off += (size_t)E * E * 2;
    float* bqkv = (float*)(ws + off);       off += (size_t)3 * E * 4;
    off = (off + 255) & ~(size_t)255;
    short* y1 = (short*)(ws + off);         off += (size_t)N * 3 * E * 2;
    short* ao = xb;  // reuse xb: dead after GEMM1

    // 1) fused conversion
    cvt_all<<<dim3(18433), dim3(256), 0, stream>>>(
        x, Wq, Wk, Wv, Wo, bq, bk, bv,
        (unsigned short*)xb, (unsigned short*)wqkv, (unsigned short*)wo, bqkv);

    // 2) QKV projection (R4-proven schedule): grid 1536 (%8==0)
    gemm_bt<true><<<dim3((N / 256) * (3 * E / 256)), dim3(512), 131072, stream>>>(
        xb, wqkv, bqkv, (unsigned short*)y1, nullptr, N, 3 * E, E);

    // 3) per-token attention
    attn_k<<<dim3(N * 16 / 256), dim3(256), 0, stream>>>(y1, ao);

    // 4) output projection (experimental frag-prefetch schedule): grid 512 (%8==0)
    gemm_pf<<<dim3((N / 256) * (E / 256)), dim3(512), 65536, stream>>>(
        ao, wo, bo, out, N, E, E);
}